// Round 1
// 294.132 us; speedup vs baseline: 1.0473x; 1.0473x over previous
//
#include <hip/hip_runtime.h>
#include <stdint.h>

// Problem constants
#define ENC2 1024   // 2*ENC_HID = K of main GEMM
#define DECH 1024
#define ADIM 1024   // N (attn dim)
#define BB   32
#define SS   1024

typedef _Float16 half_t;
typedef __attribute__((ext_vector_type(4))) _Float16 half4;
typedef __attribute__((ext_vector_type(8))) _Float16 half8;
typedef __attribute__((ext_vector_type(4))) float    f32x4;

// async global->LDS, 16B per lane; lds dest = wave-uniform base + lane*16
__device__ __forceinline__ void dma16(const half_t* g, half_t* l) {
    __builtin_amdgcn_global_load_lds((const __attribute__((address_space(1))) void*)g,
                                     (__attribute__((address_space(3))) void*)l,
                                     16, 0, 0);
}

// ---------------------------------------------------------------------------
// Section bodies (shared between fused k_prep and the fallback kernels)
// ---------------------------------------------------------------------------

// Build swizzled fp16 W_enc^T (region/chunk layout unchanged from prev round).
__device__ __forceinline__ void wt_body(int blk, int t, char* smem,
                                        const float* __restrict__ W,
                                        half_t* __restrict__ Wt2) {
    float (*tile)[257] = (float (*)[257])smem;   // 32x257 f32 = 32896 B
    const int nb = blk >> 5;   // 0..3
    const int ks = blk & 31;   // 0..31
    #pragma unroll
    for (int i = 0; i < 32; i++) {
        int idx = t + i * 256;
        int kr = idx >> 8, n = idx & 255;
        tile[kr][n] = W[(size_t)(DECH + ks * 32 + kr) * ADIM + nb * 256 + n];
    }
    __syncthreads();
    half_t* reg = Wt2 + ((size_t)(nb * 32 + ks) << 13);   // 8192 halfs/region
    #pragma unroll
    for (int i = 0; i < 4; i++) {
        int cid = t + i * 256;            // 0..1023 chunk id
        int r = cid >> 2, pos = cid & 3;
        int c = pos ^ ((r >> 1) & 3);
        half8 h;
        #pragma unroll
        for (int e = 0; e < 8; e++) h[e] = (half_t)tile[c * 8 + e][r];
        *(half8*)(reg + r * 32 + pos * 8) = h;
    }
}

// split-K stage 1 of dec_proj: 128 virtual blocks = 16 col-tiles x 8 k-chunks
__device__ __forceinline__ void dp1_body(int blk, int t, char* smem,
                                         const float* __restrict__ dh,
                                         const float* __restrict__ W,
                                         float* __restrict__ part) {
    float (*red)[BB][64] = (float (*)[BB][64])smem;   // 32 KB
    const int ct = blk & 15;
    const int kc = blk >> 4;    // 0..7
    const int col = ct * 64 + (t & 63);
    const int w = t >> 6;
    const int k0 = kc * 128 + w * 32;
    float wreg[32];
    #pragma unroll
    for (int kk = 0; kk < 32; kk++)
        wreg[kk] = W[(size_t)(k0 + kk) * ADIM + col];
    float s[BB];
    #pragma unroll
    for (int b = 0; b < BB; b++) s[b] = 0.f;
    #pragma unroll
    for (int kk = 0; kk < 32; kk++) {
        #pragma unroll
        for (int b = 0; b < BB; b++)
            s[b] += dh[b * DECH + k0 + kk] * wreg[kk];
    }
    #pragma unroll
    for (int b = 0; b < BB; b++) red[w][b][t & 63] = s[b];
    __syncthreads();
    if (t < 64) {
        for (int b = 0; b < BB; b++)
            part[((size_t)kc * BB + b) * ADIM + ct * 64 + t] =
                red[0][b][t] + red[1][b][t] + red[2][b][t] + red[3][b][t];
    }
}

// enc fp32 -> fp16, pre-permuted into k_main's dma chunk order:
// chunk = (mi*32 + ks)*8 + c,  c = quad*2 + p  (p = upper/lower 64 rows of the
// 128-row m-tile, quad = 8-half k-subgroup).  Lane l of chunk carries
// enc[mi*128 + p*64 + l][ks*32 + quad*8 .. +7] as 16 B.  2048 virtual blocks,
// each handles a 64-row x 256-col sub-tile via an LDS-staged transpose.
__device__ __forceinline__ void enc16_body(int blk, int t, char* smem,
                                           const float* __restrict__ enc,
                                           half_t* __restrict__ e16) {
    half_t (*Lt)[264] = (half_t (*)[264])smem;   // 64x264 fp16 = 33792 B (row 16B-aligned)
    const int rblk = blk >> 2, cblk = blk & 3;
    const int r0 = rblk * 64, k0 = cblk * 256;
    #pragma unroll
    for (int i = 0; i < 16; i++) {
        int row = i * 4 + (t >> 6);
        int col = (t & 63) * 4;
        float4 vv = *(const float4*)&enc[(size_t)(r0 + row) * ENC2 + k0 + col];
        half4 h;
        h[0] = (half_t)vv.x; h[1] = (half_t)vv.y;
        h[2] = (half_t)vv.z; h[3] = (half_t)vv.w;
        *(half4*)&Lt[row][col] = h;
    }
    __syncthreads();
    const int mi = rblk >> 1, p = rblk & 1;
    const int ks0 = cblk * 8;
    #pragma unroll
    for (int j = 0; j < 8; j++) {
        int u = j * 256 + t;
        int pair = u >> 6, l = u & 63;        // pair: 8 ks x 4 quads
        int ksl = pair >> 2, quad = pair & 3;
        half8 h = *(const half8*)&Lt[l][ksl * 32 + quad * 8];
        size_t chunk = (size_t)(mi * 32 + ks0 + ksl) * 8 + quad * 2 + p;
        *(half8*)&e16[(chunk << 9) + l * 8] = h;   // 1 KB contiguous per 64 lanes
    }
}

// ---------------------------------------------------------------------------
// K0 (fused prep): blocks 0..2047 enc16 permute, 2048..2175 W^T, 2176..2303 dp1
// ---------------------------------------------------------------------------
__global__ __launch_bounds__(256) void k_prep(const float* __restrict__ enc,
                                              const float* __restrict__ W,
                                              const float* __restrict__ dh,
                                              half_t* __restrict__ e16,
                                              half_t* __restrict__ Wt2,
                                              float* __restrict__ dpart) {
    __shared__ __align__(16) char smem[33792];
    const int bid = blockIdx.x;
    if (bid < 2048)       enc16_body(bid, threadIdx.x, smem, enc, e16);
    else if (bid < 2176)  wt_body(bid - 2048, threadIdx.x, smem, W, Wt2);
    else                  dp1_body(bid - 2176, threadIdx.x, smem, dh, W, dpart);
}

// ---------------------------------------------------------------------------
// K1: fused GEMM(fp16 MFMA) + tanh + dot(v) -> per-n-tile partial scores.
// m97 structure: BOTH operands staged via global_load_lds width=16, linear
// LDS dest, conflict-free ds_read_b128 (A: [quad][row]*16B -> bank = 4*row
// mod 32, exact 8-pass).  No in-loop VALU staging, no ds_write.
// dp2 (8-way split-K sum + bias) folded into the epilogue.
// ---------------------------------------------------------------------------
#define BM 128
#define BN 256
#define BK 32
#define LDA 40   // (fallback k_main_reg only)

__global__ __launch_bounds__(512, 4) void k_main(const half_t* __restrict__ encA,
                                                 const half_t* __restrict__ Wt2,
                                                 const float* __restrict__ dpart,
                                                 const float* __restrict__ bias,
                                                 const float* __restrict__ v,
                                                 float* __restrict__ scores_part) {
    __shared__ half_t lsA[2][4096];    // 16 KB: [quad(4)][row(128)] x 8 halfs
    __shared__ half_t lsB[2][8192];    // 32 KB: swizzled chunk layout

    const int bid = blockIdx.x;
    const int mi = (bid >> 5) * 8 + (bid & 7);   // 0..255
    const int nb = (bid >> 3) & 3;               // 0..3
    const int m0 = mi * BM;
    const int t = threadIdx.x;
    const int w = t >> 6, L = t & 63;
    const int wm = w & 1, wn = w >> 1;        // 2x4 wave grid, 64x64 tiles
    const int lane15 = L & 15, quad = L >> 4;

    const half_t* Abase = encA + ((size_t)mi << 17);   // mi*32 ks * 8 chunks * 512 halfs
    const half_t* Bbase = Wt2 + ((size_t)(nb * 32) << 13);

    f32x4 acc[4][4];
    #pragma unroll
    for (int i = 0; i < 4; i++)
        #pragma unroll
        for (int j = 0; j < 4; j++) acc[i][j] = (f32x4)0.f;

    auto dmaA = [&](int ks, int pb) {
        // 8 chunks of 1 KB per K-step; one per wave; LDS dest lane-linear
        dma16(Abase + (((size_t)ks * 8 + w) << 9) + L * 8, &lsA[pb][w * 512]);
    };
    auto dmaB = [&](int ks, int pb) {
        #pragma unroll
        for (int jj = 0; jj < 2; jj++) {
            int j = 2 * w + jj;
            dma16(Bbase + ((size_t)ks << 13) + j * 512 + L * 8,
                  &lsB[pb][j * 512]);
        }
    };

    // prologue
    dmaA(0, 0);
    dmaB(0, 0);
    __syncthreads();

    for (int ks = 0; ks < ENC2 / BK; ks++) {
        const int cur = ks & 1;
        if (ks < ENC2 / BK - 1) {
            dmaA(ks + 1, cur ^ 1);
            dmaB(ks + 1, cur ^ 1);
        }
        half8 af[4], bf[4];
        #pragma unroll
        for (int sm = 0; sm < 4; sm++)
            af[sm] = *(const half8*)&lsA[cur][quad * 1024 +
                                              (wm * 64 + sm * 16 + lane15) * 8];
        #pragma unroll
        for (int sn = 0; sn < 4; sn++) {
            int r = wn * 64 + sn * 16 + lane15;
            int pos = quad ^ ((r >> 1) & 3);
            bf[sn] = *(const half8*)&lsB[cur][r * 32 + pos * 8];
        }
        #pragma unroll
        for (int sm = 0; sm < 4; sm++)
            #pragma unroll
            for (int sn = 0; sn < 4; sn++)
                acc[sm][sn] = __builtin_amdgcn_mfma_f32_16x16x32_f16(
                    af[sm], bf[sn], acc[sm][sn], 0, 0, 0);
        __syncthreads();
    }

    // epilogue: dp = bias + sum_kc dpart  (k_dp2 folded in), then
    // tanh(acc + dp) . v; shuffle-reduce 16 col-lanes, LDS-reduce across wn.
    // C/D layout: row(m) = quad*4 + reg, col(n) = lane15
    const int batch = mi >> 3;
    float vv[4], dp[4];
    #pragma unroll
    for (int sn = 0; sn < 4; sn++) {
        int ng = nb * BN + wn * 64 + sn * 16 + lane15;
        vv[sn] = v[ng];
        float s = bias[ng];
        #pragma unroll
        for (int kc = 0; kc < 8; kc++)
            s += dpart[((size_t)kc * BB + batch) * ADIM + ng];
        dp[sn] = s;
    }

    float* redL = (float*)&lsA[0][0];   // [wn][128], buffer dead post-loop
    #pragma unroll
    for (int sm = 0; sm < 4; sm++) {
        #pragma unroll
        for (int rr = 0; rr < 4; rr++) {
            float s = 0.f;
            #pragma unroll
            for (int sn = 0; sn < 4; sn++) {
                float x = acc[sm][sn][rr] + dp[sn];
                float e  = __builtin_amdgcn_exp2f(x * 2.8853900817779268f);
                float th = 1.f - 2.f * __builtin_amdgcn_rcpf(e + 1.f);
                s += th * vv[sn];
            }
            s += __shfl_xor(s, 1, 64);
            s += __shfl_xor(s, 2, 64);
            s += __shfl_xor(s, 4, 64);
            s += __shfl_xor(s, 8, 64);
            if (lane15 == 0) {
                int mlocal = wm * 64 + sm * 16 + quad * 4 + rr;
                redL[wn * 128 + mlocal] = s;
            }
        }
    }
    __syncthreads();
    if (t < 128) {
        float s = redL[t] + redL[128 + t] + redL[256 + t] + redL[384 + t];
        scores_part[((size_t)nb << 15) + m0 + t] = s;
    }
}

// ---------------------------------------------------------------------------
// K2: sum 4 partials + row softmax over S=1024 per batch row
// ---------------------------------------------------------------------------
__global__ __launch_bounds__(256) void k_softmax(const float* __restrict__ sp,
                                                 float* __restrict__ out) {
    __shared__ float red[8];
    const int b = blockIdx.x, t = threadIdx.x;
    float x[4];
    #pragma unroll
    for (int i = 0; i < 4; i++) {
        size_t idx = (size_t)b * SS + t + i * 256;
        x[i] = sp[idx] + sp[(1u << 15) + idx] + sp[(2u << 15) + idx] +
               sp[(3u << 15) + idx];
    }
    float mx = fmaxf(fmaxf(x[0], x[1]), fmaxf(x[2], x[3]));
    #pragma unroll
    for (int d = 1; d < 64; d <<= 1) mx = fmaxf(mx, __shfl_xor(mx, d, 64));
    if ((t & 63) == 0) red[t >> 6] = mx;
    __syncthreads();
    mx = fmaxf(fmaxf(red[0], red[1]), fmaxf(red[2], red[3]));
    float e[4], s = 0.f;
    #pragma unroll
    for (int i = 0; i < 4; i++) {
        e[i] = __builtin_amdgcn_exp2f((x[i] - mx) * 1.4426950408889634f);
        s += e[i];
    }
    #pragma unroll
    for (int d = 1; d < 64; d <<= 1) s += __shfl_xor(s, d, 64);
    if ((t & 63) == 0) red[4 + (t >> 6)] = s;
    __syncthreads();
    s = red[4] + red[5] + red[6] + red[7];
    float inv = 1.f / s;
    #pragma unroll
    for (int i = 0; i < 4; i++) out[(size_t)b * SS + t + i * 256] = e[i] * inv;
}

// ---------------------------------------------------------------------------
// Fallback path (previous round's proven kernels) — used if ws too small
// ---------------------------------------------------------------------------
__global__ __launch_bounds__(256) void k_wt_f(const float* __restrict__ W,
                                              half_t* __restrict__ Wt2) {
    __shared__ __align__(16) char smem[32896];
    wt_body(blockIdx.x, threadIdx.x, smem, W, Wt2);
}

__global__ __launch_bounds__(256) void k_dp1_f(const float* __restrict__ dh,
                                               const float* __restrict__ W,
                                               float* __restrict__ part) {
    __shared__ __align__(16) char smem[32768];
    dp1_body(blockIdx.x, threadIdx.x, smem, dh, W, part);
}

__global__ __launch_bounds__(256) void k_dp2_f(const float* __restrict__ part,
                                               const float* __restrict__ bias,
                                               float* __restrict__ decp) {
    const int i = blockIdx.x * 256 + threadIdx.x;
    float s = bias[i & (ADIM - 1)];
    #pragma unroll
    for (int kc = 0; kc < 8; kc++)
        s += part[(size_t)kc * BB * ADIM + i];
    decp[i] = s;
}

__global__ __launch_bounds__(512, 4) void k_main_reg(const float* __restrict__ enc,
                                                     const half_t* __restrict__ Wt2,
                                                     const float* __restrict__ decp,
                                                     const float* __restrict__ v,
                                                     float* __restrict__ scores_part) {
    __shared__ half_t lsA[2][BM][LDA];
    __shared__ half_t lsB[2][BN * BK];

    const int bid = blockIdx.x;
    const int mi = (bid >> 5) * 8 + (bid & 7);
    const int nb = (bid >> 3) & 3;
    const int m0 = mi * BM;
    const int t = threadIdx.x;
    const int w = t >> 6, L = t & 63;
    const int wm = w & 1, wn = w >> 1;
    const int lane15 = L & 15, quad = L >> 4;

    const int arow = t & 127;
    const int akc  = (t >> 7) * 8;
    const float* Aptr = enc + (size_t)(m0 + arow) * ENC2 + akc;
    const half_t* Bbase = Wt2 + ((size_t)(nb * 32) << 13);

    f32x4 acc[4][4];
    #pragma unroll
    for (int i = 0; i < 4; i++)
        #pragma unroll
        for (int j = 0; j < 4; j++) acc[i][j] = (f32x4)0.f;

    float4 ra0, ra1;
    auto loadA = [&](int ks) {
        const float* p = Aptr + ks * BK;
        ra0 = *(const float4*)p;
        ra1 = *(const float4*)(p + 4);
    };
    auto writeA = [&](int pb) {
        half8 ha;
        ha[0] = (half_t)ra0.x; ha[1] = (half_t)ra0.y;
        ha[2] = (half_t)ra0.z; ha[3] = (half_t)ra0.w;
        ha[4] = (half_t)ra1.x; ha[5] = (half_t)ra1.y;
        ha[6] = (half_t)ra1.z; ha[7] = (half_t)ra1.w;
        *(half8*)&lsA[pb][arow][akc] = ha;
    };
    auto dmaB = [&](int ks, int pb) {
        #pragma unroll
        for (int jj = 0; jj < 2; jj++) {
            int j = 2 * w + jj;
            dma16(Bbase + ((size_t)ks << 13) + j * 512 + L * 8,
                  &lsB[pb][j * 512]);
        }
    };

    dmaB(0, 0);
    loadA(0);
    writeA(0);
    loadA(1);
    __syncthreads();

    for (int ks = 0; ks < ENC2 / BK; ks++) {
        const int cur = ks & 1;
        if (ks < ENC2 / BK - 1) {
            dmaB(ks + 1, cur ^ 1);
            writeA(cur ^ 1);
            if (ks < ENC2 / BK - 2) loadA(ks + 2);
        }
        half8 af[4], bf[4];
        #pragma unroll
        for (int sm = 0; sm < 4; sm++)
            af[sm] = *(const half8*)&lsA[cur][wm * 64 + sm * 16 + lane15][quad * 8];
        #pragma unroll
        for (int sn = 0; sn < 4; sn++) {
            int r = wn * 64 + sn * 16 + lane15;
            int pos = quad ^ ((r >> 1) & 3);
            bf[sn] = *(const half8*)&lsB[cur][r * 32 + pos * 8];
        }
        #pragma unroll
        for (int sm = 0; sm < 4; sm++)
            #pragma unroll
            for (int sn = 0; sn < 4; sn++)
                acc[sm][sn] = __builtin_amdgcn_mfma_f32_16x16x32_f16(
                    af[sm], bf[sn], acc[sm][sn], 0, 0, 0);
        __syncthreads();
    }

    const int batch = mi >> 3;
    float vv[4], dp[4];
    #pragma unroll
    for (int sn = 0; sn < 4; sn++) {
        int ng = nb * BN + wn * 64 + sn * 16 + lane15;
        vv[sn] = v[ng];
        dp[sn] = decp[(size_t)batch * ADIM + ng];
    }

    float* redL = (float*)&lsA[0][0][0];
    #pragma unroll
    for (int sm = 0; sm < 4; sm++) {
        #pragma unroll
        for (int rr = 0; rr < 4; rr++) {
            float s = 0.f;
            #pragma unroll
            for (int sn = 0; sn < 4; sn++) {
                float x = acc[sm][sn][rr] + dp[sn];
                float e  = __builtin_amdgcn_exp2f(x * 2.8853900817779268f);
                float th = 1.f - 2.f * __builtin_amdgcn_rcpf(e + 1.f);
                s += th * vv[sn];
            }
            s += __shfl_xor(s, 1, 64);
            s += __shfl_xor(s, 2, 64);
            s += __shfl_xor(s, 4, 64);
            s += __shfl_xor(s, 8, 64);
            if (lane15 == 0) {
                int mlocal = wm * 64 + sm * 16 + quad * 4 + rr;
                redL[wn * 128 + mlocal] = s;
            }
        }
    }
    __syncthreads();
    if (t < 128) {
        float s = redL[t] + redL[128 + t] + redL[256 + t] + redL[384 + t];
        scores_part[((size_t)nb << 15) + m0 + t] = s;
    }
}

// ---------------------------------------------------------------------------
extern "C" void kernel_launch(void* const* d_in, const int* in_sizes, int n_in,
                              void* d_out, int out_size, void* d_ws, size_t ws_size,
                              hipStream_t stream) {
    const float* dh   = (const float*)d_in[0];  // (32,1024)
    const float* enc  = (const float*)d_in[1];  // (32,1024,1024)
    const float* W    = (const float*)d_in[2];  // (2048,1024)
    const float* bias = (const float*)d_in[3];  // (1024,)
    const float* v    = (const float*)d_in[4];  // (1024,)
    float* out = (float*)d_out;

    char* ws = (char*)d_ws;
    const size_t E16_BYTES = (size_t)BB * SS * ENC2 * sizeof(half_t);  // 64 MB
    const size_t NEED = (4u << 20) + E16_BYTES;                        // 68 MB

    if (ws_size >= NEED) {
        // new path layout
        half_t* Wt2   = (half_t*)ws;                         // 2 MB
        float*  dpart = (float*)(ws + (2u << 20));           // 1 MB
        float*  spart = (float*)(ws + (3u << 20));           // 512 KB
        half_t* e16   = (half_t*)(ws + (4u << 20));          // 64 MB

        k_prep   <<<2304, 256, 0, stream>>>(enc, W, dh, e16, Wt2, dpart);
        k_main   <<<1024, 512, 0, stream>>>(e16, Wt2, dpart, bias, v, spart);
        k_softmax<<<32, 256, 0, stream>>>(spart, out);
    } else {
        // fallback: previous round's proven 5-kernel path
        half_t* Wt2   = (half_t*)ws;                                     // 2 MB
        float*  decp  = (float*)(ws + 2u * 1024 * 1024);                 // 128 KB
        float*  spart = (float*)(ws + 2u * 1024 * 1024 + 128 * 1024);    // 512 KB
        float*  dpart = (float*)(ws + 2u * 1024 * 1024 + 640 * 1024);    // 1 MB

        k_wt_f   <<<128, 256, 0, stream>>>(W, Wt2);
        k_dp1_f  <<<128, 256, 0, stream>>>(dh, W, dpart);
        k_dp2_f  <<<128, 256, 0, stream>>>(dpart, bias, decp);
        k_main_reg<<<1024, 512, 0, stream>>>(enc, Wt2, decp, v, spart);
        k_softmax<<<32, 256, 0, stream>>>(spart, out);
    }
}

// Round 2
// 283.482 us; speedup vs baseline: 1.0867x; 1.0376x over previous
//
#include <hip/hip_runtime.h>
#include <stdint.h>

// Problem constants
#define ENC2 1024   // 2*ENC_HID = K of main GEMM
#define DECH 1024
#define ADIM 1024   // N (attn dim)
#define BB   32
#define SS   1024

typedef _Float16 half_t;
typedef __attribute__((ext_vector_type(4))) _Float16 half4;
typedef __attribute__((ext_vector_type(8))) _Float16 half8;
typedef __attribute__((ext_vector_type(4))) float    f32x4;

// async global->LDS, 16B per lane; lds dest = wave-uniform base + lane*16
__device__ __forceinline__ void dma16(const half_t* g, half_t* l) {
    __builtin_amdgcn_global_load_lds((const __attribute__((address_space(1))) void*)g,
                                     (__attribute__((address_space(3))) void*)l,
                                     16, 0, 0);
}

// ---------------------------------------------------------------------------
// K0 (fused prep, 512 threads/block):
//   blocks 0..2047  : enc fp32 -> fp16 permute into k_main chunk order
//   blocks 2048..2175: swizzled fp16 W_enc^T
//   blocks 2176..2303: dec_proj split-K stage 1 (256-thread body, guarded)
// 512 thr @ 33.8 KB LDS -> 4 blocks/CU x 8 waves = 32 waves/CU (100% cap);
// round-1's 256-thr version capped at 16 waves (measured Occupancy 23%,
// 1.65 TB/s, latency-bound).
// ---------------------------------------------------------------------------
__global__ __launch_bounds__(512) void k_prep(const float* __restrict__ enc,
                                              const float* __restrict__ W,
                                              const float* __restrict__ dh,
                                              half_t* __restrict__ e16,
                                              half_t* __restrict__ Wt2,
                                              float* __restrict__ dpart) {
    __shared__ __align__(16) char smem[33792];
    const int bid = blockIdx.x;
    const int t = threadIdx.x;

    if (bid < 2048) {
        // ---- enc16: 64 rows x 256 cols per block, LDS-staged transpose ----
        // chunk = (mi*32 + ks)*8 + quad*2 + p; lane l of chunk carries
        // enc[mi*128 + p*64 + l][ks*32 + quad*8 .. +7] as 16 B.
        half_t (*Lt)[264] = (half_t (*)[264])smem;   // 64x264 fp16 (rows 16B-aligned)
        const int rblk = bid >> 2, cblk = bid & 3;
        const int r0 = rblk * 64, k0 = cblk * 256;
        #pragma unroll
        for (int i = 0; i < 8; i++) {
            int row = i * 8 + (t >> 6);          // wave-uniform row
            int col = (t & 63) * 4;              // 64 lanes x 16B contiguous
            float4 vv = *(const float4*)&enc[(size_t)(r0 + row) * ENC2 + k0 + col];
            half4 h;
            h[0] = (half_t)vv.x; h[1] = (half_t)vv.y;
            h[2] = (half_t)vv.z; h[3] = (half_t)vv.w;
            *(half4*)&Lt[row][col] = h;
        }
        __syncthreads();
        const int mi = rblk >> 1, p = rblk & 1;
        const int ks0 = cblk * 8;
        #pragma unroll
        for (int j = 0; j < 4; j++) {
            int u = j * 512 + t;
            int pair = u >> 6, l = u & 63;       // pair: 8 ksl x 4 quads
            int ksl = pair >> 2, quad = pair & 3;
            half8 h = *(const half8*)&Lt[l][ksl * 32 + quad * 8];
            size_t chunk = (size_t)(mi * 32 + ks0 + ksl) * 8 + quad * 2 + p;
            *(half8*)&e16[(chunk << 9) + l * 8];  // address check (no-op)
            *(half8*)&e16[(chunk << 9) + l * 8] = h;   // 1 KB contiguous / wave
        }
    } else if (bid < 2176) {
        // ---- W_enc^T swizzle (512-thread re-index of round-0 k_wt) ----
        float (*tile)[257] = (float (*)[257])smem;   // 32x257 f32 = 32896 B
        const int blk = bid - 2048;
        const int nb = blk >> 5;   // 0..3
        const int ks = blk & 31;   // 0..31
        #pragma unroll
        for (int i = 0; i < 16; i++) {
            int idx = t + i * 512;
            int kr = idx >> 8, n = idx & 255;
            tile[kr][n] = W[(size_t)(DECH + ks * 32 + kr) * ADIM + nb * 256 + n];
        }
        __syncthreads();
        half_t* reg = Wt2 + ((size_t)(nb * 32 + ks) << 13);   // 8192 halfs/region
        #pragma unroll
        for (int i = 0; i < 2; i++) {
            int cid = t + i * 512;            // 0..1023 chunk id
            int r = cid >> 2, pos = cid & 3;
            int c = pos ^ ((r >> 1) & 3);
            half8 h;
            #pragma unroll
            for (int e = 0; e < 8; e++) h[e] = (half_t)tile[c * 8 + e][r];
            *(half8*)(reg + r * 32 + pos * 8) = h;
        }
    } else {
        // ---- dec_proj split-K stage 1 (256-thread body, uniform barriers) ----
        float (*red)[BB][64] = (float (*)[BB][64])smem;   // 32 KB
        const int blk = bid - 2176;
        const int ct = blk & 15;
        const int kc = blk >> 4;    // 0..7
        if (t < 256) {
            const int col = ct * 64 + (t & 63);
            const int w = t >> 6;                // 0..3
            const int k0 = kc * 128 + w * 32;
            float wreg[32];
            #pragma unroll
            for (int kk = 0; kk < 32; kk++)
                wreg[kk] = W[(size_t)(k0 + kk) * ADIM + col];
            float s[BB];
            #pragma unroll
            for (int b = 0; b < BB; b++) s[b] = 0.f;
            #pragma unroll
            for (int kk = 0; kk < 32; kk++) {
                #pragma unroll
                for (int b = 0; b < BB; b++)
                    s[b] += dh[b * DECH + k0 + kk] * wreg[kk];
            }
            #pragma unroll
            for (int b = 0; b < BB; b++) red[w][b][t & 63] = s[b];
        }
        __syncthreads();
        if (t < 64) {
            for (int b = 0; b < BB; b++)
                dpart[((size_t)kc * BB + b) * ADIM + ct * 64 + t] =
                    red[0][b][t] + red[1][b][t] + red[2][b][t] + red[3][b][t];
        }
    }
}

// ---------------------------------------------------------------------------
// K1: fused GEMM(fp16 MFMA) + tanh + dot(v) -> per-n-tile partial scores.
// m97 structure: BOTH operands staged via global_load_lds width=16, linear
// LDS dest, conflict-free ds_read_b128.  dp2 folded into the epilogue.
// (unchanged from round 1 — measured <86 us, ~the 128x256 structure ceiling)
// ---------------------------------------------------------------------------
#define BM 128
#define BN 256
#define BK 32

__global__ __launch_bounds__(512, 4) void k_main(const half_t* __restrict__ encA,
                                                 const half_t* __restrict__ Wt2,
                                                 const float* __restrict__ dpart,
                                                 const float* __restrict__ bias,
                                                 const float* __restrict__ v,
                                                 float* __restrict__ scores_part) {
    __shared__ half_t lsA[2][4096];    // 16 KB: [quad(4)][row(128)] x 8 halfs
    __shared__ half_t lsB[2][8192];    // 32 KB: swizzled chunk layout

    const int bid = blockIdx.x;
    const int mi = (bid >> 5) * 8 + (bid & 7);   // 0..255
    const int nb = (bid >> 3) & 3;               // 0..3
    const int m0 = mi * BM;
    const int t = threadIdx.x;
    const int w = t >> 6, L = t & 63;
    const int wm = w & 1, wn = w >> 1;        // 2x4 wave grid, 64x64 tiles
    const int lane15 = L & 15, quad = L >> 4;

    const half_t* Abase = encA + ((size_t)mi << 17);
    const half_t* Bbase = Wt2 + ((size_t)(nb * 32) << 13);

    f32x4 acc[4][4];
    #pragma unroll
    for (int i = 0; i < 4; i++)
        #pragma unroll
        for (int j = 0; j < 4; j++) acc[i][j] = (f32x4)0.f;

    auto dmaA = [&](int ks, int pb) {
        dma16(Abase + (((size_t)ks * 8 + w) << 9) + L * 8, &lsA[pb][w * 512]);
    };
    auto dmaB = [&](int ks, int pb) {
        #pragma unroll
        for (int jj = 0; jj < 2; jj++) {
            int j = 2 * w + jj;
            dma16(Bbase + ((size_t)ks << 13) + j * 512 + L * 8,
                  &lsB[pb][j * 512]);
        }
    };

    // prologue
    dmaA(0, 0);
    dmaB(0, 0);
    __syncthreads();

    for (int ks = 0; ks < ENC2 / BK; ks++) {
        const int cur = ks & 1;
        if (ks < ENC2 / BK - 1) {
            dmaA(ks + 1, cur ^ 1);
            dmaB(ks + 1, cur ^ 1);
        }
        half8 af[4], bf[4];
        #pragma unroll
        for (int sm = 0; sm < 4; sm++)
            af[sm] = *(const half8*)&lsA[cur][quad * 1024 +
                                              (wm * 64 + sm * 16 + lane15) * 8];
        #pragma unroll
        for (int sn = 0; sn < 4; sn++) {
            int r = wn * 64 + sn * 16 + lane15;
            int pos = quad ^ ((r >> 1) & 3);
            bf[sn] = *(const half8*)&lsB[cur][r * 32 + pos * 8];
        }
        #pragma unroll
        for (int sm = 0; sm < 4; sm++)
            #pragma unroll
            for (int sn = 0; sn < 4; sn++)
                acc[sm][sn] = __builtin_amdgcn_mfma_f32_16x16x32_f16(
                    af[sm], bf[sn], acc[sm][sn], 0, 0, 0);
        __syncthreads();
    }

    // epilogue: dp = bias + sum_kc dpart, then tanh(acc + dp) . v;
    // shuffle-reduce 16 col-lanes, LDS-reduce across wn.
    // C/D layout: row(m) = quad*4 + reg, col(n) = lane15
    const int batch = mi >> 3;
    float vv[4], dp[4];
    #pragma unroll
    for (int sn = 0; sn < 4; sn++) {
        int ng = nb * BN + wn * 64 + sn * 16 + lane15;
        vv[sn] = v[ng];
        float s = bias[ng];
        #pragma unroll
        for (int kc = 0; kc < 8; kc++)
            s += dpart[((size_t)kc * BB + batch) * ADIM + ng];
        dp[sn] = s;
    }

    float* redL = (float*)&lsA[0][0];   // [wn][128], buffer dead post-loop
    #pragma unroll
    for (int sm = 0; sm < 4; sm++) {
        #pragma unroll
        for (int rr = 0; rr < 4; rr++) {
            float s = 0.f;
            #pragma unroll
            for (int sn = 0; sn < 4; sn++) {
                float x = acc[sm][sn][rr] + dp[sn];
                float e  = __builtin_amdgcn_exp2f(x * 2.8853900817779268f);
                float th = 1.f - 2.f * __builtin_amdgcn_rcpf(e + 1.f);
                s += th * vv[sn];
            }
            s += __shfl_xor(s, 1, 64);
            s += __shfl_xor(s, 2, 64);
            s += __shfl_xor(s, 4, 64);
            s += __shfl_xor(s, 8, 64);
            if (lane15 == 0) {
                int mlocal = wm * 64 + sm * 16 + quad * 4 + rr;
                redL[wn * 128 + mlocal] = s;
            }
        }
    }
    __syncthreads();
    if (t < 128) {
        float s = redL[t] + redL[128 + t] + redL[256 + t] + redL[384 + t];
        scores_part[((size_t)nb << 15) + m0 + t] = s;
    }
}

// ---------------------------------------------------------------------------
// K2: sum 4 partials + row softmax over S=1024 per batch row
// ---------------------------------------------------------------------------
__global__ __launch_bounds__(256) void k_softmax(const float* __restrict__ sp,
                                                 float* __restrict__ out) {
    __shared__ float red[8];
    const int b = blockIdx.x, t = threadIdx.x;
    float x[4];
    #pragma unroll
    for (int i = 0; i < 4; i++) {
        size_t idx = (size_t)b * SS + t + i * 256;
        x[i] = sp[idx] + sp[(1u << 15) + idx] + sp[(2u << 15) + idx] +
               sp[(3u << 15) + idx];
    }
    float mx = fmaxf(fmaxf(x[0], x[1]), fmaxf(x[2], x[3]));
    #pragma unroll
    for (int d = 1; d < 64; d <<= 1) mx = fmaxf(mx, __shfl_xor(mx, d, 64));
    if ((t & 63) == 0) red[t >> 6] = mx;
    __syncthreads();
    mx = fmaxf(fmaxf(red[0], red[1]), fmaxf(red[2], red[3]));
    float e[4], s = 0.f;
    #pragma unroll
    for (int i = 0; i < 4; i++) {
        e[i] = __builtin_amdgcn_exp2f((x[i] - mx) * 1.4426950408889634f);
        s += e[i];
    }
    #pragma unroll
    for (int d = 1; d < 64; d <<= 1) s += __shfl_xor(s, d, 64);
    if ((t & 63) == 0) red[4 + (t >> 6)] = s;
    __syncthreads();
    s = red[4] + red[5] + red[6] + red[7];
    float inv = 1.f / s;
    #pragma unroll
    for (int i = 0; i < 4; i++) out[(size_t)b * SS + t + i * 256] = e[i] * inv;
}

// ---------------------------------------------------------------------------
// Fallback path (round-0 proven kernels, self-contained 256-thread versions)
// ---------------------------------------------------------------------------
__global__ __launch_bounds__(256) void k_wt_f(const float* __restrict__ W,
                                              half_t* __restrict__ Wt2) {
    __shared__ float tile[32][257];
    const int nb = blockIdx.x >> 5;
    const int ks = blockIdx.x & 31;
    const int t = threadIdx.x;
    #pragma unroll
    for (int i = 0; i < 32; i++) {
        int idx = t + i * 256;
        int kr = idx >> 8, n = idx & 255;
        tile[kr][n] = W[(size_t)(DECH + ks * 32 + kr) * ADIM + nb * 256 + n];
    }
    __syncthreads();
    half_t* reg = Wt2 + ((size_t)(nb * 32 + ks) << 13);
    #pragma unroll
    for (int i = 0; i < 4; i++) {
        int cid = t + i * 256;
        int r = cid >> 2, pos = cid & 3;
        int c = pos ^ ((r >> 1) & 3);
        half8 h;
        #pragma unroll
        for (int e = 0; e < 8; e++) h[e] = (half_t)tile[c * 8 + e][r];
        *(half8*)(reg + r * 32 + pos * 8) = h;
    }
}

__global__ __launch_bounds__(256) void k_dp1_f(const float* __restrict__ dh,
                                               const float* __restrict__ W,
                                               float* __restrict__ part) {
    __shared__ float red[4][BB][64];
    const int t = threadIdx.x;
    const int ct = blockIdx.x & 15;
    const int kc = blockIdx.x >> 4;
    const int col = ct * 64 + (t & 63);
    const int w = t >> 6;
    const int k0 = kc * 128 + w * 32;
    float wreg[32];
    #pragma unroll
    for (int kk = 0; kk < 32; kk++)
        wreg[kk] = W[(size_t)(k0 + kk) * ADIM + col];
    float s[BB];
    #pragma unroll
    for (int b = 0; b < BB; b++) s[b] = 0.f;
    #pragma unroll
    for (int kk = 0; kk < 32; kk++) {
        #pragma unroll
        for (int b = 0; b < BB; b++)
            s[b] += dh[b * DECH + k0 + kk] * wreg[kk];
    }
    #pragma unroll
    for (int b = 0; b < BB; b++) red[w][b][t & 63] = s[b];
    __syncthreads();
    if (t < 64) {
        for (int b = 0; b < BB; b++)
            part[((size_t)kc * BB + b) * ADIM + ct * 64 + t] =
                red[0][b][t] + red[1][b][t] + red[2][b][t] + red[3][b][t];
    }
}

__global__ __launch_bounds__(256) void k_dp2_f(const float* __restrict__ part,
                                               const float* __restrict__ bias,
                                               float* __restrict__ decp) {
    const int i = blockIdx.x * 256 + threadIdx.x;
    float s = bias[i & (ADIM - 1)];
    #pragma unroll
    for (int kc = 0; kc < 8; kc++)
        s += part[(size_t)kc * BB * ADIM + i];
    decp[i] = s;
}

#define LDA 40
__global__ __launch_bounds__(512, 4) void k_main_reg(const float* __restrict__ enc,
                                                     const half_t* __restrict__ Wt2,
                                                     const float* __restrict__ decp,
                                                     const float* __restrict__ v,
                                                     float* __restrict__ scores_part) {
    __shared__ half_t lsA[2][BM][LDA];
    __shared__ half_t lsB[2][BN * BK];

    const int bid = blockIdx.x;
    const int mi = (bid >> 5) * 8 + (bid & 7);
    const int nb = (bid >> 3) & 3;
    const int m0 = mi * BM;
    const int t = threadIdx.x;
    const int w = t >> 6, L = t & 63;
    const int wm = w & 1, wn = w >> 1;
    const int lane15 = L & 15, quad = L >> 4;

    const int arow = t & 127;
    const int akc  = (t >> 7) * 8;
    const float* Aptr = enc + (size_t)(m0 + arow) * ENC2 + akc;
    const half_t* Bbase = Wt2 + ((size_t)(nb * 32) << 13);

    f32x4 acc[4][4];
    #pragma unroll
    for (int i = 0; i < 4; i++)
        #pragma unroll
        for (int j = 0; j < 4; j++) acc[i][j] = (f32x4)0.f;

    float4 ra0, ra1;
    auto loadA = [&](int ks) {
        const float* p = Aptr + ks * BK;
        ra0 = *(const float4*)p;
        ra1 = *(const float4*)(p + 4);
    };
    auto writeA = [&](int pb) {
        half8 ha;
        ha[0] = (half_t)ra0.x; ha[1] = (half_t)ra0.y;
        ha[2] = (half_t)ra0.z; ha[3] = (half_t)ra0.w;
        ha[4] = (half_t)ra1.x; ha[5] = (half_t)ra1.y;
        ha[6] = (half_t)ra1.z; ha[7] = (half_t)ra1.w;
        *(half8*)&lsA[pb][arow][akc] = ha;
    };
    auto dmaB = [&](int ks, int pb) {
        #pragma unroll
        for (int jj = 0; jj < 2; jj++) {
            int j = 2 * w + jj;
            dma16(Bbase + ((size_t)ks << 13) + j * 512 + L * 8,
                  &lsB[pb][j * 512]);
        }
    };

    dmaB(0, 0);
    loadA(0);
    writeA(0);
    loadA(1);
    __syncthreads();

    for (int ks = 0; ks < ENC2 / BK; ks++) {
        const int cur = ks & 1;
        if (ks < ENC2 / BK - 1) {
            dmaB(ks + 1, cur ^ 1);
            writeA(cur ^ 1);
            if (ks < ENC2 / BK - 2) loadA(ks + 2);
        }
        half8 af[4], bf[4];
        #pragma unroll
        for (int sm = 0; sm < 4; sm++)
            af[sm] = *(const half8*)&lsA[cur][wm * 64 + sm * 16 + lane15][quad * 8];
        #pragma unroll
        for (int sn = 0; sn < 4; sn++) {
            int r = wn * 64 + sn * 16 + lane15;
            int pos = quad ^ ((r >> 1) & 3);
            bf[sn] = *(const half8*)&lsB[cur][r * 32 + pos * 8];
        }
        #pragma unroll
        for (int sm = 0; sm < 4; sm++)
            #pragma unroll
            for (int sn = 0; sn < 4; sn++)
                acc[sm][sn] = __builtin_amdgcn_mfma_f32_16x16x32_f16(
                    af[sm], bf[sn], acc[sm][sn], 0, 0, 0);
        __syncthreads();
    }

    const int batch = mi >> 3;
    float vv[4], dp[4];
    #pragma unroll
    for (int sn = 0; sn < 4; sn++) {
        int ng = nb * BN + wn * 64 + sn * 16 + lane15;
        vv[sn] = v[ng];
        dp[sn] = decp[(size_t)batch * ADIM + ng];
    }

    float* redL = (float*)&lsA[0][0][0];
    #pragma unroll
    for (int sm = 0; sm < 4; sm++) {
        #pragma unroll
        for (int rr = 0; rr < 4; rr++) {
            float s = 0.f;
            #pragma unroll
            for (int sn = 0; sn < 4; sn++) {
                float x = acc[sm][sn][rr] + dp[sn];
                float e  = __builtin_amdgcn_exp2f(x * 2.8853900817779268f);
                float th = 1.f - 2.f * __builtin_amdgcn_rcpf(e + 1.f);
                s += th * vv[sn];
            }
            s += __shfl_xor(s, 1, 64);
            s += __shfl_xor(s, 2, 64);
            s += __shfl_xor(s, 4, 64);
            s += __shfl_xor(s, 8, 64);
            if (lane15 == 0) {
                int mlocal = wm * 64 + sm * 16 + quad * 4 + rr;
                redL[wn * 128 + mlocal] = s;
            }
        }
    }
    __syncthreads();
    if (t < 128) {
        float s = redL[t] + redL[128 + t] + redL[256 + t] + redL[384 + t];
        scores_part[((size_t)nb << 15) + m0 + t] = s;
    }
}

// ---------------------------------------------------------------------------
extern "C" void kernel_launch(void* const* d_in, const int* in_sizes, int n_in,
                              void* d_out, int out_size, void* d_ws, size_t ws_size,
                              hipStream_t stream) {
    const float* dh   = (const float*)d_in[0];  // (32,1024)
    const float* enc  = (const float*)d_in[1];  // (32,1024,1024)
    const float* W    = (const float*)d_in[2];  // (2048,1024)
    const float* bias = (const float*)d_in[3];  // (1024,)
    const float* v    = (const float*)d_in[4];  // (1024,)
    float* out = (float*)d_out;

    char* ws = (char*)d_ws;
    const size_t E16_BYTES = (size_t)BB * SS * ENC2 * sizeof(half_t);  // 64 MB
    const size_t NEED = (4u << 20) + E16_BYTES;                        // 68 MB

    if (ws_size >= NEED) {
        half_t* Wt2   = (half_t*)ws;                         // 2 MB
        float*  dpart = (float*)(ws + (2u << 20));           // 1 MB
        float*  spart = (float*)(ws + (3u << 20));           // 512 KB
        half_t* e16   = (half_t*)(ws + (4u << 20));          // 64 MB

        k_prep   <<<2304, 512, 0, stream>>>(enc, W, dh, e16, Wt2, dpart);
        k_main   <<<1024, 512, 0, stream>>>(e16, Wt2, dpart, bias, v, spart);
        k_softmax<<<32, 256, 0, stream>>>(spart, out);
    } else {
        // fallback: round-0 proven 5-kernel path
        half_t* Wt2   = (half_t*)ws;                                     // 2 MB
        float*  decp  = (float*)(ws + 2u * 1024 * 1024);                 // 128 KB
        float*  spart = (float*)(ws + 2u * 1024 * 1024 + 128 * 1024);    // 512 KB
        float*  dpart = (float*)(ws + 2u * 1024 * 1024 + 640 * 1024);    // 1 MB

        k_wt_f   <<<128, 256, 0, stream>>>(W, Wt2);
        k_dp1_f  <<<128, 256, 0, stream>>>(dh, W, dpart);
        k_dp2_f  <<<128, 256, 0, stream>>>(dpart, bias, decp);
        k_main_reg<<<1024, 512, 0, stream>>>(enc, Wt2, decp, v, spart);
        k_softmax<<<32, 256, 0, stream>>>(spart, out);
    }
}

// Round 3
// 281.306 us; speedup vs baseline: 1.0951x; 1.0077x over previous
//
#include <hip/hip_runtime.h>
#include <stdint.h>

// Problem constants
#define ENC2 1024   // 2*ENC_HID = K of main GEMM
#define DECH 1024
#define ADIM 1024   // N (attn dim)
#define BB   32
#define SS   1024

typedef _Float16 half_t;
typedef __attribute__((ext_vector_type(4))) _Float16 half4;
typedef __attribute__((ext_vector_type(8))) _Float16 half8;
typedef __attribute__((ext_vector_type(4))) float    f32x4;

// async global->LDS, 16B per lane; lds dest = wave-uniform base + lane*16
__device__ __forceinline__ void dma16(const half_t* g, half_t* l) {
    __builtin_amdgcn_global_load_lds((const __attribute__((address_space(1))) void*)g,
                                     (__attribute__((address_space(3))) void*)l,
                                     16, 0, 0);
}

// counted waits (raw, compiler must not reorder across)  [T4 idiom + rule #18]
#define VM6()   asm volatile("s_waitcnt vmcnt(6)" ::: "memory")
#define VM3()   asm volatile("s_waitcnt vmcnt(3)" ::: "memory")
#define VM0()   asm volatile("s_waitcnt vmcnt(0)" ::: "memory")
#define LGKM0() asm volatile("s_waitcnt lgkmcnt(0)" ::: "memory")
#define SCHED0() __builtin_amdgcn_sched_barrier(0)
#define RBAR()  __builtin_amdgcn_s_barrier()

// ---------------------------------------------------------------------------
// K0 (fused prep, 512 threads/block):
//   blocks 0..2047  : enc fp32 -> fp16 permute into k_main chunk order
//   blocks 2048..2175: swizzled fp16 W_enc^T
//   blocks 2176..2303: dec_proj split-K stage 1 (256-thread body, guarded)
// (unchanged from round 2 — dropped below the 78 us fill in top-5)
// ---------------------------------------------------------------------------
__global__ __launch_bounds__(512) void k_prep(const float* __restrict__ enc,
                                              const float* __restrict__ W,
                                              const float* __restrict__ dh,
                                              half_t* __restrict__ e16,
                                              half_t* __restrict__ Wt2,
                                              float* __restrict__ dpart) {
    __shared__ __align__(16) char smem[33792];
    const int bid = blockIdx.x;
    const int t = threadIdx.x;

    if (bid < 2048) {
        // ---- enc16: 64 rows x 256 cols per block, LDS-staged transpose ----
        // chunk = (mi*32 + ks)*8 + quad*2 + p; lane l of chunk carries
        // enc[mi*128 + p*64 + l][ks*32 + quad*8 .. +7] as 16 B.
        half_t (*Lt)[264] = (half_t (*)[264])smem;   // 64x264 fp16 (rows 16B-aligned)
        const int rblk = bid >> 2, cblk = bid & 3;
        const int r0 = rblk * 64, k0 = cblk * 256;
        #pragma unroll
        for (int i = 0; i < 8; i++) {
            int row = i * 8 + (t >> 6);          // wave-uniform row
            int col = (t & 63) * 4;              // 64 lanes x 16B contiguous
            float4 vv = *(const float4*)&enc[(size_t)(r0 + row) * ENC2 + k0 + col];
            half4 h;
            h[0] = (half_t)vv.x; h[1] = (half_t)vv.y;
            h[2] = (half_t)vv.z; h[3] = (half_t)vv.w;
            *(half4*)&Lt[row][col] = h;
        }
        __syncthreads();
        const int mi = rblk >> 1, p = rblk & 1;
        const int ks0 = cblk * 8;
        #pragma unroll
        for (int j = 0; j < 4; j++) {
            int u = j * 512 + t;
            int pair = u >> 6, l = u & 63;       // pair: 8 ksl x 4 quads
            int ksl = pair >> 2, quad = pair & 3;
            half8 h = *(const half8*)&Lt[l][ksl * 32 + quad * 8];
            size_t chunk = (size_t)(mi * 32 + ks0 + ksl) * 8 + quad * 2 + p;
            *(half8*)&e16[(chunk << 9) + l * 8] = h;   // 1 KB contiguous / wave
        }
    } else if (bid < 2176) {
        // ---- W_enc^T swizzle ----
        float (*tile)[257] = (float (*)[257])smem;   // 32x257 f32 = 32896 B
        const int blk = bid - 2048;
        const int nb = blk >> 5;   // 0..3
        const int ks = blk & 31;   // 0..31
        #pragma unroll
        for (int i = 0; i < 16; i++) {
            int idx = t + i * 512;
            int kr = idx >> 8, n = idx & 255;
            tile[kr][n] = W[(size_t)(DECH + ks * 32 + kr) * ADIM + nb * 256 + n];
        }
        __syncthreads();
        half_t* reg = Wt2 + ((size_t)(nb * 32 + ks) << 13);   // 8192 halfs/region
        #pragma unroll
        for (int i = 0; i < 2; i++) {
            int cid = t + i * 512;            // 0..1023 chunk id
            int r = cid >> 2, pos = cid & 3;
            int c = pos ^ ((r >> 1) & 3);
            half8 h;
            #pragma unroll
            for (int e = 0; e < 8; e++) h[e] = (half_t)tile[c * 8 + e][r];
            *(half8*)(reg + r * 32 + pos * 8) = h;
        }
    } else {
        // ---- dec_proj split-K stage 1 (256-thread body, uniform barriers) ----
        float (*red)[BB][64] = (float (*)[BB][64])smem;   // 32 KB
        const int blk = bid - 2176;
        const int ct = blk & 15;
        const int kc = blk >> 4;    // 0..7
        if (t < 256) {
            const int col = ct * 64 + (t & 63);
            const int w = t >> 6;                // 0..3
            const int k0 = kc * 128 + w * 32;
            float wreg[32];
            #pragma unroll
            for (int kk = 0; kk < 32; kk++)
                wreg[kk] = W[(size_t)(k0 + kk) * ADIM + col];
            float s[BB];
            #pragma unroll
            for (int b = 0; b < BB; b++) s[b] = 0.f;
            #pragma unroll
            for (int kk = 0; kk < 32; kk++) {
                #pragma unroll
                for (int b = 0; b < BB; b++)
                    s[b] += dh[b * DECH + k0 + kk] * wreg[kk];
            }
            #pragma unroll
            for (int b = 0; b < BB; b++) red[w][b][t & 63] = s[b];
        }
        __syncthreads();
        if (t < 64) {
            for (int b = 0; b < BB; b++)
                dpart[((size_t)kc * BB + b) * ADIM + ct * 64 + t] =
                    red[0][b][t] + red[1][b][t] + red[2][b][t] + red[3][b][t];
        }
    }
}

// ---------------------------------------------------------------------------
// K1: fused GEMM(fp16 MFMA) + tanh + dot(v) -> per-n-tile partial scores.
// ROUND 3: triple-buffered K-loop with counted vmcnt across RAW barriers
// (T4, prefetch distance 2).  __syncthreads' mandatory vmcnt(0) drain was
// the residual ~20% stall of the 2-deep structure (m139: distance-1 null;
// distance-2 needs 3 buffers).  Safety argument:
//   - stage(ks+2) writes buf[(ks+2)%3] == buf[(ks-1)%3]; all waves finished
//     reading it at the end-of-iter barrier of ks-1.
//   - VM6 after issuing stage(ks+2): own outstanding <= 9 (stages ks..ks+2),
//     so >=3 oldest (= stage ks) complete; the following barrier makes this
//     wave-global.  Tail: VM3 @ks=30, VM0 @ks=31.
//   - ds_reads of buf[ks%3] are drained by LGKM0 before the trailing raw
//     barrier, ahead of any wave's next-iter dma issue into that buffer.
// ---------------------------------------------------------------------------
#define BM 128
#define BN 256
#define BK 32

__global__ __launch_bounds__(512, 4) void k_main(const half_t* __restrict__ encA,
                                                 const half_t* __restrict__ Wt2,
                                                 const float* __restrict__ dpart,
                                                 const float* __restrict__ bias,
                                                 const float* __restrict__ v,
                                                 float* __restrict__ scores_part) {
    __shared__ half_t lsA[3][4096];    // 24 KB: [quad(4)][row(128)] x 8 halfs
    __shared__ half_t lsB[3][8192];    // 48 KB: swizzled chunk layout

    const int bid = blockIdx.x;
    const int mi = (bid >> 5) * 8 + (bid & 7);   // 0..255
    const int nb = (bid >> 3) & 3;               // 0..3
    const int m0 = mi * BM;
    const int t = threadIdx.x;
    const int w = t >> 6, L = t & 63;
    const int wm = w & 1, wn = w >> 1;        // 2x4 wave grid, 64x64 tiles
    const int lane15 = L & 15, quad = L >> 4;

    const half_t* Abase = encA + ((size_t)mi << 17);
    const half_t* Bbase = Wt2 + ((size_t)(nb * 32) << 13);

    f32x4 acc[4][4];
    #pragma unroll
    for (int i = 0; i < 4; i++)
        #pragma unroll
        for (int j = 0; j < 4; j++) acc[i][j] = (f32x4)0.f;

    auto stage = [&](int ks, int pb) {
        // 3 dma / thread / K-tile (1 A + 2 B), lane-linear LDS dest
        dma16(Abase + (((size_t)ks * 8 + w) << 9) + L * 8, &lsA[pb][w * 512]);
        #pragma unroll
        for (int jj = 0; jj < 2; jj++) {
            int j = 2 * w + jj;
            dma16(Bbase + ((size_t)ks << 13) + j * 512 + L * 8,
                  &lsB[pb][j * 512]);
        }
    };

    // prologue: tiles 0 and 1 in flight (distance 2)
    stage(0, 0);
    stage(1, 1);

    int cur = 0;
    for (int ks = 0; ks < ENC2 / BK; ks++) {
        const int nxt = (cur == 0) ? 2 : cur - 1;   // (ks+2) % 3
        if (ks < ENC2 / BK - 2) {
            stage(ks + 2, nxt);
            VM6();
        } else if (ks == ENC2 / BK - 2) {
            VM3();
        } else {
            VM0();
        }
        RBAR();
        SCHED0();

        half8 af[4], bf[4];
        #pragma unroll
        for (int sm = 0; sm < 4; sm++)
            af[sm] = *(const half8*)&lsA[cur][quad * 1024 +
                                              (wm * 64 + sm * 16 + lane15) * 8];
        #pragma unroll
        for (int sn = 0; sn < 4; sn++) {
            int r = wn * 64 + sn * 16 + lane15;
            int pos = quad ^ ((r >> 1) & 3);
            bf[sn] = *(const half8*)&lsB[cur][r * 32 + pos * 8];
        }
        LGKM0();
        SCHED0();
        #pragma unroll
        for (int sm = 0; sm < 4; sm++)
            #pragma unroll
            for (int sn = 0; sn < 4; sn++)
                acc[sm][sn] = __builtin_amdgcn_mfma_f32_16x16x32_f16(
                    af[sm], bf[sn], acc[sm][sn], 0, 0, 0);
        RBAR();
        cur = (cur == 2) ? 0 : cur + 1;
    }

    // epilogue: dp = bias + sum_kc dpart, then tanh(acc + dp) . v;
    // shuffle-reduce 16 col-lanes, LDS-reduce across wn.
    // C/D layout: row(m) = quad*4 + reg, col(n) = lane15
    const int batch = mi >> 3;
    float vv[4], dp[4];
    #pragma unroll
    for (int sn = 0; sn < 4; sn++) {
        int ng = nb * BN + wn * 64 + sn * 16 + lane15;
        vv[sn] = v[ng];
        float s = bias[ng];
        #pragma unroll
        for (int kc = 0; kc < 8; kc++)
            s += dpart[((size_t)kc * BB + batch) * ADIM + ng];
        dp[sn] = s;
    }

    float* redL = (float*)&lsA[0][0];   // [wn][128], buffer dead post-loop
    #pragma unroll
    for (int sm = 0; sm < 4; sm++) {
        #pragma unroll
        for (int rr = 0; rr < 4; rr++) {
            float s = 0.f;
            #pragma unroll
            for (int sn = 0; sn < 4; sn++) {
                float x = acc[sm][sn][rr] + dp[sn];
                float e  = __builtin_amdgcn_exp2f(x * 2.8853900817779268f);
                float th = 1.f - 2.f * __builtin_amdgcn_rcpf(e + 1.f);
                s += th * vv[sn];
            }
            s += __shfl_xor(s, 1, 64);
            s += __shfl_xor(s, 2, 64);
            s += __shfl_xor(s, 4, 64);
            s += __shfl_xor(s, 8, 64);
            if (lane15 == 0) {
                int mlocal = wm * 64 + sm * 16 + quad * 4 + rr;
                redL[wn * 128 + mlocal] = s;
            }
        }
    }
    __syncthreads();
    if (t < 128) {
        float s = redL[t] + redL[128 + t] + redL[256 + t] + redL[384 + t];
        scores_part[((size_t)nb << 15) + m0 + t] = s;
    }
}

// ---------------------------------------------------------------------------
// K2: sum 4 partials + row softmax over S=1024 per batch row
// ---------------------------------------------------------------------------
__global__ __launch_bounds__(256) void k_softmax(const float* __restrict__ sp,
                                                 float* __restrict__ out) {
    __shared__ float red[8];
    const int b = blockIdx.x, t = threadIdx.x;
    float x[4];
    #pragma unroll
    for (int i = 0; i < 4; i++) {
        size_t idx = (size_t)b * SS + t + i * 256;
        x[i] = sp[idx] + sp[(1u << 15) + idx] + sp[(2u << 15) + idx] +
               sp[(3u << 15) + idx];
    }
    float mx = fmaxf(fmaxf(x[0], x[1]), fmaxf(x[2], x[3]));
    #pragma unroll
    for (int d = 1; d < 64; d <<= 1) mx = fmaxf(mx, __shfl_xor(mx, d, 64));
    if ((t & 63) == 0) red[t >> 6] = mx;
    __syncthreads();
    mx = fmaxf(fmaxf(red[0], red[1]), fmaxf(red[2], red[3]));
    float e[4], s = 0.f;
    #pragma unroll
    for (int i = 0; i < 4; i++) {
        e[i] = __builtin_amdgcn_exp2f((x[i] - mx) * 1.4426950408889634f);
        s += e[i];
    }
    #pragma unroll
    for (int d = 1; d < 64; d <<= 1) s += __shfl_xor(s, d, 64);
    if ((t & 63) == 0) red[4 + (t >> 6)] = s;
    __syncthreads();
    s = red[4] + red[5] + red[6] + red[7];
    float inv = 1.f / s;
    #pragma unroll
    for (int i = 0; i < 4; i++) out[(size_t)b * SS + t + i * 256] = e[i] * inv;
}

// ---------------------------------------------------------------------------
// Fallback path (round-0 proven kernels, self-contained 256-thread versions)
// ---------------------------------------------------------------------------
__global__ __launch_bounds__(256) void k_wt_f(const float* __restrict__ W,
                                              half_t* __restrict__ Wt2) {
    __shared__ float tile[32][257];
    const int nb = blockIdx.x >> 5;
    const int ks = blockIdx.x & 31;
    const int t = threadIdx.x;
    #pragma unroll
    for (int i = 0; i < 32; i++) {
        int idx = t + i * 256;
        int kr = idx >> 8, n = idx & 255;
        tile[kr][n] = W[(size_t)(DECH + ks * 32 + kr) * ADIM + nb * 256 + n];
    }
    __syncthreads();
    half_t* reg = Wt2 + ((size_t)(nb * 32 + ks) << 13);
    #pragma unroll
    for (int i = 0; i < 4; i++) {
        int cid = t + i * 256;
        int r = cid >> 2, pos = cid & 3;
        int c = pos ^ ((r >> 1) & 3);
        half8 h;
        #pragma unroll
        for (int e = 0; e < 8; e++) h[e] = (half_t)tile[c * 8 + e][r];
        *(half8*)(reg + r * 32 + pos * 8) = h;
    }
}

__global__ __launch_bounds__(256) void k_dp1_f(const float* __restrict__ dh,
                                               const float* __restrict__ W,
                                               float* __restrict__ part) {
    __shared__ float red[4][BB][64];
    const int t = threadIdx.x;
    const int ct = blockIdx.x & 15;
    const int kc = blockIdx.x >> 4;
    const int col = ct * 64 + (t & 63);
    const int w = t >> 6;
    const int k0 = kc * 128 + w * 32;
    float wreg[32];
    #pragma unroll
    for (int kk = 0; kk < 32; kk++)
        wreg[kk] = W[(size_t)(k0 + kk) * ADIM + col];
    float s[BB];
    #pragma unroll
    for (int b = 0; b < BB; b++) s[b] = 0.f;
    #pragma unroll
    for (int kk = 0; kk < 32; kk++) {
        #pragma unroll
        for (int b = 0; b < BB; b++)
            s[b] += dh[b * DECH + k0 + kk] * wreg[kk];
    }
    #pragma unroll
    for (int b = 0; b < BB; b++) red[w][b][t & 63] = s[b];
    __syncthreads();
    if (t < 64) {
        for (int b = 0; b < BB; b++)
            part[((size_t)kc * BB + b) * ADIM + ct * 64 + t] =
                red[0][b][t] + red[1][b][t] + red[2][b][t] + red[3][b][t];
    }
}

__global__ __launch_bounds__(256) void k_dp2_f(const float* __restrict__ part,
                                               const float* __restrict__ bias,
                                               float* __restrict__ decp) {
    const int i = blockIdx.x * 256 + threadIdx.x;
    float s = bias[i & (ADIM - 1)];
    #pragma unroll
    for (int kc = 0; kc < 8; kc++)
        s += part[(size_t)kc * BB * ADIM + i];
    decp[i] = s;
}

#define LDA 40
__global__ __launch_bounds__(512, 4) void k_main_reg(const float* __restrict__ enc,
                                                     const half_t* __restrict__ Wt2,
                                                     const float* __restrict__ decp,
                                                     const float* __restrict__ v,
                                                     float* __restrict__ scores_part) {
    __shared__ half_t lsA[2][BM][LDA];
    __shared__ half_t lsB[2][BN * BK];

    const int bid = blockIdx.x;
    const int mi = (bid >> 5) * 8 + (bid & 7);
    const int nb = (bid >> 3) & 3;
    const int m0 = mi * BM;
    const int t = threadIdx.x;
    const int w = t >> 6, L = t & 63;
    const int wm = w & 1, wn = w >> 1;
    const int lane15 = L & 15, quad = L >> 4;

    const int arow = t & 127;
    const int akc  = (t >> 7) * 8;
    const float* Aptr = enc + (size_t)(m0 + arow) * ENC2 + akc;
    const half_t* Bbase = Wt2 + ((size_t)(nb * 32) << 13);

    f32x4 acc[4][4];
    #pragma unroll
    for (int i = 0; i < 4; i++)
        #pragma unroll
        for (int j = 0; j < 4; j++) acc[i][j] = (f32x4)0.f;

    float4 ra0, ra1;
    auto loadA = [&](int ks) {
        const float* p = Aptr + ks * BK;
        ra0 = *(const float4*)p;
        ra1 = *(const float4*)(p + 4);
    };
    auto writeA = [&](int pb) {
        half8 ha;
        ha[0] = (half_t)ra0.x; ha[1] = (half_t)ra0.y;
        ha[2] = (half_t)ra0.z; ha[3] = (half_t)ra0.w;
        ha[4] = (half_t)ra1.x; ha[5] = (half_t)ra1.y;
        ha[6] = (half_t)ra1.z; ha[7] = (half_t)ra1.w;
        *(half8*)&lsA[pb][arow][akc] = ha;
    };
    auto dmaB = [&](int ks, int pb) {
        #pragma unroll
        for (int jj = 0; jj < 2; jj++) {
            int j = 2 * w + jj;
            dma16(Bbase + ((size_t)ks << 13) + j * 512 + L * 8,
                  &lsB[pb][j * 512]);
        }
    };

    dmaB(0, 0);
    loadA(0);
    writeA(0);
    loadA(1);
    __syncthreads();

    for (int ks = 0; ks < ENC2 / BK; ks++) {
        const int cur = ks & 1;
        if (ks < ENC2 / BK - 1) {
            dmaB(ks + 1, cur ^ 1);
            writeA(cur ^ 1);
            if (ks < ENC2 / BK - 2) loadA(ks + 2);
        }
        half8 af[4], bf[4];
        #pragma unroll
        for (int sm = 0; sm < 4; sm++)
            af[sm] = *(const half8*)&lsA[cur][wm * 64 + sm * 16 + lane15][quad * 8];
        #pragma unroll
        for (int sn = 0; sn < 4; sn++) {
            int r = wn * 64 + sn * 16 + lane15;
            int pos = quad ^ ((r >> 1) & 3);
            bf[sn] = *(const half8*)&lsB[cur][r * 32 + pos * 8];
        }
        #pragma unroll
        for (int sm = 0; sm < 4; sm++)
            #pragma unroll
            for (int sn = 0; sn < 4; sn++)
                acc[sm][sn] = __builtin_amdgcn_mfma_f32_16x16x32_f16(
                    af[sm], bf[sn], acc[sm][sn], 0, 0, 0);
        __syncthreads();
    }

    const int batch = mi >> 3;
    float vv[4], dp[4];
    #pragma unroll
    for (int sn = 0; sn < 4; sn++) {
        int ng = nb * BN + wn * 64 + sn * 16 + lane15;
        vv[sn] = v[ng];
        dp[sn] = decp[(size_t)batch * ADIM + ng];
    }

    float* redL = (float*)&lsA[0][0][0];
    #pragma unroll
    for (int sm = 0; sm < 4; sm++) {
        #pragma unroll
        for (int rr = 0; rr < 4; rr++) {
            float s = 0.f;
            #pragma unroll
            for (int sn = 0; sn < 4; sn++) {
                float x = acc[sm][sn][rr] + dp[sn];
                float e  = __builtin_amdgcn_exp2f(x * 2.8853900817779268f);
                float th = 1.f - 2.f * __builtin_amdgcn_rcpf(e + 1.f);
                s += th * vv[sn];
            }
            s += __shfl_xor(s, 1, 64);
            s += __shfl_xor(s, 2, 64);
            s += __shfl_xor(s, 4, 64);
            s += __shfl_xor(s, 8, 64);
            if (lane15 == 0) {
                int mlocal = wm * 64 + sm * 16 + quad * 4 + rr;
                redL[wn * 128 + mlocal] = s;
            }
        }
    }
    __syncthreads();
    if (t < 128) {
        float s = redL[t] + redL[128 + t] + redL[256 + t] + redL[384 + t];
        scores_part[((size_t)nb << 15) + m0 + t] = s;
    }
}

// ---------------------------------------------------------------------------
extern "C" void kernel_launch(void* const* d_in, const int* in_sizes, int n_in,
                              void* d_out, int out_size, void* d_ws, size_t ws_size,
                              hipStream_t stream) {
    const float* dh   = (const float*)d_in[0];  // (32,1024)
    const float* enc  = (const float*)d_in[1];  // (32,1024,1024)
    const float* W    = (const float*)d_in[2];  // (2048,1024)
    const float* bias = (const float*)d_in[3];  // (1024,)
    const float* v    = (const float*)d_in[4];  // (1024,)
    float* out = (float*)d_out;

    char* ws = (char*)d_ws;
    const size_t E16_BYTES = (size_t)BB * SS * ENC2 * sizeof(half_t);  // 64 MB
    const size_t NEED = (4u << 20) + E16_BYTES;                        // 68 MB

    if (ws_size >= NEED) {
        half_t* Wt2   = (half_t*)ws;                         // 2 MB
        float*  dpart = (float*)(ws + (2u << 20));           // 1 MB
        float*  spart = (float*)(ws + (3u << 20));           // 512 KB
        half_t* e16   = (half_t*)(ws + (4u << 20));          // 64 MB

        k_prep   <<<2304, 512, 0, stream>>>(enc, W, dh, e16, Wt2, dpart);
        k_main   <<<1024, 512, 0, stream>>>(e16, Wt2, dpart, bias, v, spart);
        k_softmax<<<32, 256, 0, stream>>>(spart, out);
    } else {
        // fallback: round-0 proven 5-kernel path
        half_t* Wt2   = (half_t*)ws;                                     // 2 MB
        float*  decp  = (float*)(ws + 2u * 1024 * 1024);                 // 128 KB
        float*  spart = (float*)(ws + 2u * 1024 * 1024 + 128 * 1024);    // 512 KB
        float*  dpart = (float*)(ws + 2u * 1024 * 1024 + 640 * 1024);    // 1 MB

        k_wt_f   <<<128, 256, 0, stream>>>(W, Wt2);
        k_dp1_f  <<<128, 256, 0, stream>>>(dh, W, dpart);
        k_dp2_f  <<<128, 256, 0, stream>>>(dpart, bias, decp);
        k_main_reg<<<1024, 512, 0, stream>>>(enc, Wt2, decp, v, spart);
        k_softmax<<<32, 256, 0, stream>>>(spart, out);
    }
}